// Round 5
// baseline (116.491 us; speedup 1.0000x reference)
//
#include <hip/hip_runtime.h>

// Pairwise cosine similarity: C[i][j] = <x_i/||x_i||, y_j/||y_j||>
// x,y: [8192][512] f32.  Out: [8192][8192] f32.
// Stage 1: row-normalize -> bf16 in d_ws (xn 8MB + yn 8MB).
// Stage 2: 256x256-tile 8-phase bf16 MFMA GEMM (T1+T2+T3+T4+T5):
//   BK=64, 8 waves (2Mx4N), 128KB dbuf LDS, counted vmcnt(4),
//   XOR-swizzled LDS staging, setprio, XCD 4-row-band L2 ordering.
// R5 change (single variable): block-cooperative epilogue producing
//   FULL-WAVE-CONTIGUOUS 1KB stores (64 lanes x 16B, fillBuffer-shaped).
//   R1-R3 showed FETCH_SIZE == output size invariant to store width/nt:
//   hypothesis = TCC store-miss line allocation not elided for
//   quarter-wave 256B runs; the harness fill (1KB/wave-instr contiguous)
//   shows FETCH ~= 0, so we replicate its geometry exactly.

typedef __attribute__((ext_vector_type(8))) short bf16x8;
typedef __attribute__((ext_vector_type(4))) float f32x4;
typedef __attribute__((ext_vector_type(8))) unsigned short ushort8;

#define M_DIM 8192
#define N_DIM 8192
#define K_DIM 512

static __device__ __forceinline__ unsigned short f32_to_bf16(float f) {
  unsigned int u = __float_as_uint(f);
  u = (u + 0x7FFFu + ((u >> 16) & 1u)) >> 16;  // round-to-nearest-even
  return (unsigned short)u;
}

__global__ __launch_bounds__(256) void normalize_rows(
    const float* __restrict__ in, unsigned short* __restrict__ out) {
  const int wid = threadIdx.x >> 6;
  const int lane = threadIdx.x & 63;
  const int row = (blockIdx.x << 2) + wid;
  const float4* r = (const float4*)(in + (size_t)row * K_DIM);
  float4 v0 = r[lane * 2];
  float4 v1 = r[lane * 2 + 1];
  float ss = v0.x * v0.x + v0.y * v0.y + v0.z * v0.z + v0.w * v0.w +
             v1.x * v1.x + v1.y * v1.y + v1.z * v1.z + v1.w * v1.w;
#pragma unroll
  for (int off = 32; off; off >>= 1) ss += __shfl_xor(ss, off, 64);
  const float s = 1.0f / fmaxf(sqrtf(ss), 1e-8f);
  const float f[8] = {v0.x, v0.y, v0.z, v0.w, v1.x, v1.y, v1.z, v1.w};
  union { ushort8 v; unsigned short u[8]; } o;
#pragma unroll
  for (int i = 0; i < 8; ++i) o.u[i] = f32_to_bf16(f[i] * s);
  *(ushort8*)(out + (size_t)row * K_DIM + lane * 8) = o.v;
}

static __device__ __forceinline__ void gl16(const unsigned short* g, char* l) {
  __builtin_amdgcn_global_load_lds(
      (const __attribute__((address_space(1))) unsigned int*)g,
      (__attribute__((address_space(3))) unsigned int*)l, 16, 0, 0);
}

#define BAR() __builtin_amdgcn_s_barrier()
#define SBAR() __builtin_amdgcn_sched_barrier(0)
#define LGKM0() do { asm volatile("s_waitcnt lgkmcnt(0)" ::: "memory"); \
                     __builtin_amdgcn_sched_barrier(0); } while (0)
#define VMCNT(n) do { asm volatile("s_waitcnt vmcnt(" #n ")" ::: "memory"); \
                      __builtin_amdgcn_sched_barrier(0); } while (0)

__global__ __launch_bounds__(512, 2) void cosgemm(
    const unsigned short* __restrict__ A,   // xn bf16 [8192][512]
    const unsigned short* __restrict__ B,   // yn bf16 [8192][512]
    float* __restrict__ C) {                // [8192][8192]
  extern __shared__ char smem[];  // 128KB: buf[2] x {A 32K, B 32K}

  const int tid = threadIdx.x;
  const int lane = tid & 63;
  const int wid = tid >> 6;
  const int wm = wid >> 2;        // 0..1  (M half)
  const int wn = wid & 3;         // 0..3  (N quarter)
  const int lr16 = lane & 15;
  const int hq = lane >> 4;       // 0..3
  const int x7 = lane & 7;

  // XCD band ordering: 4 consecutive by per XCD, sweep bx; B panel reused
  // by 4 resident blocks, A band (1MB) L2-resident.
  const int bid = blockIdx.x;
  const int L = bid >> 3;                   // 0..127
  const int by = ((bid & 7) << 2) + (L & 3);
  const int bx = L >> 2;
  const int row0 = by << 8;
  const int col0 = bx << 8;

  // staging: row = c*64 + tid/8, 16B slot = (tid&7) ^ (row&7) (rule #21)
  const int rl = tid >> 3;
  const int sl = (tid & 7) ^ (rl & 7);
  const unsigned short* qA[2], * qB[2];
  qA[0] = A + (size_t)(row0 + rl) * K_DIM + sl * 8;
  qA[1] = A + (size_t)(row0 + 64 + rl) * K_DIM + sl * 8;
  qB[0] = B + (size_t)(col0 + rl) * K_DIM + sl * 8;
  qB[1] = B + (size_t)(col0 + 64 + rl) * K_DIM + sl * 8;

  auto stage = [&](int op, int half, int t) {  // one half-tile = 2 gload_lds
    const unsigned short* g0 = (op ? qB[0] : qA[0]) + half * 65536 + t * 64;
    const unsigned short* g1 = (op ? qB[1] : qA[1]) + half * 65536 + t * 64;
    char* l = smem + ((t & 1) << 16) + (op << 15) + (half << 14) + (wid << 10);
    gl16(g0, l);
    gl16(g1, l + 8192);
  };

  bf16x8 af[4][2], bf[4][2];
  f32x4 acc[8][4] = {};

  auto ldA = [&](int t, int fmBase) {   // 8 x ds_read_b128
#pragma unroll
    for (int j = 0; j < 4; ++j) {
      const char* base = smem + ((t & 1) << 16) + (wm << 14) +
                         ((fmBase + j) * 16 + lr16) * 128;
#pragma unroll
      for (int kk = 0; kk < 2; ++kk)
        af[j][kk] = *(const bf16x8*)(base + ((((kk << 2) | hq) ^ x7) << 4));
    }
  };
  auto ldB = [&](int t, int fnBase) {   // 4 x ds_read_b128
#pragma unroll
    for (int j = 0; j < 2; ++j) {
      const char* base = smem + ((t & 1) << 16) + 32768 + ((wn >> 1) << 14) +
                         (((wn & 1) << 6) + (fnBase + j) * 16 + lr16) * 128;
#pragma unroll
      for (int kk = 0; kk < 2; ++kk)
        bf[fnBase + j][kk] =
            *(const bf16x8*)(base + ((((kk << 2) | hq) ^ x7) << 4));
    }
  };
  auto mm = [&](int fmBase, int fnBase) {  // 16 MFMA
    __builtin_amdgcn_s_setprio(1);
#pragma unroll
    for (int m = 0; m < 4; ++m)
#pragma unroll
      for (int n = 0; n < 2; ++n)
#pragma unroll
        for (int kk = 0; kk < 2; ++kk)
          acc[fmBase + m][fnBase + n] = __builtin_amdgcn_mfma_f32_16x16x32_bf16(
              af[m][kk], bf[fnBase + n][kk], acc[fmBase + m][fnBase + n], 0, 0, 0);
    __builtin_amdgcn_s_setprio(0);
  };

  // ---- prologue: tile0 complete + tile1 B-halves; confirm tile0 landed
  stage(0, 0, 0); stage(0, 1, 0); stage(1, 0, 0); stage(1, 1, 0);
  stage(1, 0, 1); stage(1, 1, 1);
  VMCNT(4);
  BAR(); SBAR();

#pragma unroll
  for (int i = 0; i < 4; ++i) {
    const int t = 2 * i, u = 2 * i + 1;
    // P1
    ldA(t, 0); ldB(t, 0); stage(0, 0, u);
    BAR(); LGKM0(); mm(0, 0); BAR();
    // P2
    ldB(t, 2); stage(0, 1, u);
    BAR(); LGKM0(); mm(0, 2); BAR();
    // P3
    ldA(t, 4); if (i < 3) stage(1, 0, t + 2);
    BAR(); LGKM0(); mm(4, 0); BAR();
    // P4
    if (i < 3) stage(1, 1, t + 2);
    BAR(); LGKM0(); mm(4, 2);
    if (i < 3) { VMCNT(4); } else { VMCNT(0); }
    BAR(); SBAR();
    // P5
    ldA(u, 0); ldB(u, 0); if (i < 3) stage(0, 0, t + 2);
    BAR(); LGKM0(); mm(0, 0); BAR();
    // P6
    ldB(u, 2); if (i < 3) stage(0, 1, t + 2);
    BAR(); LGKM0(); mm(0, 2); BAR();
    // P7
    ldA(u, 4); if (i < 3) stage(1, 0, t + 3);
    BAR(); LGKM0(); mm(4, 0); BAR();
    // P8
    if (i < 3) stage(1, 1, t + 3);
    BAR(); LGKM0(); mm(4, 2);
    if (i < 3) { VMCNT(4); }
    BAR(); SBAR();
  }

  // ---- R5 epilogue: block-cooperative transpose, full-wave 1KB stores ----
  // Two strips [16][260] f32 (wm=0 band, wm=1 band), 16640B each.
  // Per fm: sync; scatter acc via ds_write; sync; each wave reads one full
  // strip row (64 lanes x 16B contiguous) and stores 1KB contiguous to C —
  // identical geometry to the harness fill (which shows FETCH ~= 0).
  float* const S = (float*)smem;
  float* const Sw = S + wm * 4160;            // my wm strip (4160 f32)
#pragma unroll
  for (int fm = 0; fm < 8; ++fm) {
    __syncthreads();  // strips free (prev fm readback consumed)
#pragma unroll
    for (int fn = 0; fn < 4; ++fn)
#pragma unroll
      for (int q = 0; q < 4; ++q)
        Sw[(hq * 4 + q) * 260 + (wn << 6) + (fn << 4) + lr16] = acc[fm][fn][q];
    __syncthreads();  // scatter visible
#pragma unroll
    for (int r = 0; r < 4; ++r) {
      const int R = r * 8 + wid;        // 0..31 flat strip-row index
      const int s = R >> 4;             // which strip (wm band)
      const int row = R & 15;
      f32x4 v = *(const f32x4*)&S[s * 4160 + row * 260 + lane * 4];
      *(f32x4*)&C[(size_t)(row0 + (s << 7) + (fm << 4) + row) * N_DIM +
                  col0 + lane * 4] = v;
    }
  }
}

extern "C" void kernel_launch(void* const* d_in, const int* in_sizes, int n_in,
                              void* d_out, int out_size, void* d_ws, size_t ws_size,
                              hipStream_t stream) {
  const float* x = (const float*)d_in[0];
  const float* y = (const float*)d_in[1];
  float* out = (float*)d_out;
  unsigned short* xn = (unsigned short*)d_ws;                    // 8 MB
  unsigned short* yn = xn + (size_t)M_DIM * K_DIM;               // 8 MB

  (void)hipFuncSetAttribute((const void*)cosgemm,
                            hipFuncAttributeMaxDynamicSharedMemorySize, 131072);

  normalize_rows<<<M_DIM / 4, 256, 0, stream>>>(x, xn);
  normalize_rows<<<N_DIM / 4, 256, 0, stream>>>(y, yn);
  cosgemm<<<(M_DIM / 256) * (N_DIM / 256), 512, 131072, stream>>>(xn, yn, out);
}